// Round 3
// baseline (208.804 us; speedup 1.0000x reference)
//
#include <hip/hip_runtime.h>
#include <hip/hip_fp16.h>
#include <math.h>

#define NNODES 65536
#define NEDGES 2097152
#define PGRAPH 1024
#define NGRAPH 64
#define CAPB   9216    /* per-(graph,quarter) bucket cap: mean 8192, sigma~90 -> +11 sigma */
#define CAPQ   9728    /* per-quarter CSR cap: mean 8192 + align-pad<=768 + 8.5 sigma      */

/* ws layout (bytes) */
#define OFF_GFILL 0u          /* int[256]  per-bucket fill                 */
#define OFF_ARR   1024u       /* int[128]  arrive1[64], arrive2[64]        */
#define OFF_POOL4 1536u       /* float[256*32] partial pools -> 34304      */
#define OFF_EBUF  34304u      /* uint[256*CAPB] = 9437184 -> 9471488       */
#define OFF_HS1   9471488u    /* uint[65536*16] = 4194304 -> 13665792      */
#define OFF_HS2   13665792u   /* uint[65536*16] = 4194304 -> 17860096      */

__device__ __forceinline__ float ftanh(float x) {
    float e = __expf(2.f * x);
    return 1.f - 2.f * __builtin_amdgcn_rcpf(e + 1.f);
}

/* read channels 4q..4q+3 of swizzled f16x2 row r */
__device__ __forceinline__ float4 ld4h(const unsigned int* hs, int r, int q) {
    uint2 u = *(const uint2*)(hs + r * 16 + ((q ^ (r & 7)) << 1));
    float2 fa = __half22float2(*(const __half2*)&u.x);
    float2 fb = __half22float2(*(const __half2*)&u.y);
    return make_float4(fa.x, fa.y, fb.x, fb.y);
}

/* ---- bucket edges by (graph, dst-quarter): 256 buckets, block-local counting sort ---- */
__global__ void k_bucket(const int* __restrict__ src, const int* __restrict__ dst,
                         int* __restrict__ gfill, unsigned int* __restrict__ ebuf) {
    __shared__ unsigned int sorted[8192];
    __shared__ int hist[256], lexcl[256], gbase[256], lfill[256];
    __shared__ int wsum[4];
    int t = threadIdx.x;
    hist[t] = 0; lfill[t] = 0;
    __syncthreads();

    const int4* src4 = (const int4*)(src + blockIdx.x * 8192);
    const int4* dst4 = (const int4*)(dst + blockIdx.x * 8192);
    unsigned int pk[32];
    #pragma unroll
    for (int k = 0; k < 8; k++) {
        int4 s4 = src4[k * 256 + t];
        int4 d4 = dst4[k * 256 + t];
        int ss[4] = { s4.x, s4.y, s4.z, s4.w };
        int dd[4] = { d4.x, d4.y, d4.z, d4.w };
        #pragma unroll
        for (int j = 0; j < 4; j++) {
            int g = ss[j] >> 10;
            pk[k * 4 + j] = (unsigned int)((ss[j] & 1023) | ((dd[j] & 1023) << 10) | (g << 20));
            int b = (g << 2) | ((dd[j] >> 8) & 3);
            atomicAdd(&hist[b], 1);
        }
    }
    __syncthreads();

    int h = hist[t];
    int lane = t & 63, wid = t >> 6;
    int xx = h;
    #pragma unroll
    for (int off = 1; off < 64; off <<= 1) {
        int y = __shfl_up(xx, off, 64);
        if (lane >= off) xx += y;
    }
    if (lane == 63) wsum[wid] = xx;
    __syncthreads();
    {
        int pre = 0;
        for (int w = 0; w < wid; w++) pre += wsum[w];
        lexcl[t] = pre + xx - h;
        gbase[t] = atomicAdd(&gfill[t], h);
    }
    __syncthreads();

    #pragma unroll
    for (int k = 0; k < 32; k++) {
        int b = pk[k] >> 18;
        int pos = lexcl[b] + atomicAdd(&lfill[b], 1);
        sorted[pos] = pk[k];
    }
    __syncthreads();
    for (int i = t; i < 8192; i += 256) {
        unsigned int p = sorted[i];
        int b = p >> 18;
        ebuf[(size_t)b * CAPB + gbase[b] + (i - lexcl[b])] = p;
    }
}

/* ---- fused GCN, single-staged: each quarter-block stages hs for ITS 256 nodes
   only (f16x2-packed), exchanges staged rows via L2 (agent-scope release/acquire
   flags -> correct regardless of XCD placement), gathers both layers from a
   65.6KB LDS hs table + LDS CSR, then Wl+pool. LDS 126KB > 80KB forces
   1 block/CU -> all 256 blocks co-resident on the 256-CU chip. */
__global__ __launch_bounds__(1024, 1) void k_gcn(
        const float* __restrict__ x,
        const float* __restrict__ W1, const float* __restrict__ b1,
        const float* __restrict__ W2, const float* __restrict__ b2,
        const float* __restrict__ Wl, const float* __restrict__ bl,
        const unsigned int* __restrict__ ebuf, const int* __restrict__ gfill,
        unsigned int* __restrict__ hs1g, unsigned int* __restrict__ hs2g,
        int* __restrict__ arrive, float* __restrict__ pooled4) {
    __shared__ unsigned int hsLh[1025 * 16];   /* 65600 B, row 1024 = zeros */
    __shared__ unsigned short lcsr[CAPQ];      /* 19456 B */
    __shared__ float h1T[32 * 257];            /* 32896 B, transposed own h  */
    __shared__ float W2L[32 * 33];             /* 4224 B  */
    __shared__ float disL[256];
    __shared__ int hist[256], lrow[256], lfill[256];
    __shared__ int wsum[4];

    int t = threadIdx.x;
    int g = blockIdx.x & 63, part = blockIdx.x >> 6;
    int bkt = (g << 2) | part;
    int cnt = gfill[bkt];
    const unsigned int* eb = ebuf + (size_t)bkt * CAPB;

    int nl = t >> 2, og = t & 3;
    /* preload own x quarter early; latency hides under the edge scan */
    float4 v4 = ((const float4*)(x + ((size_t)((g << 10) + (part << 8) + nl)) * 16))[og];

    if (t < 256) hist[t] = 0;
    W2L[(t >> 5) * 33 + (t & 31)] = W2[t];
    if (t < 16) hsLh[1024 * 16 + t] = 0u;
    __syncthreads();

    /* pass 1: degree hist over own bucket */
    for (int i = t; i < cnt; i += 1024) atomicAdd(&hist[(eb[i] >> 10) & 255], 1);
    __syncthreads();
    if (t < 256) disL[t] = rsqrtf((float)(hist[t] + 1));
    __syncthreads();

    /* stage hs1 = dis*(x@W1^T) for OWN 256 nodes (4 lanes/node, 8 ch each) */
    float xk[16];
    #pragma unroll
    for (int d = 0; d < 4; d++) {
        xk[4*d+0] = __shfl(v4.x, d, 4);
        xk[4*d+1] = __shfl(v4.y, d, 4);
        xk[4*d+2] = __shfl(v4.z, d, 4);
        xk[4*d+3] = __shfl(v4.w, d, 4);
    }
    int ln = (part << 8) + nl;
    int s7own = ln & 7;
    {
        float dnl = disL[nl];
        unsigned int uo[4];
        #pragma unroll
        for (int p2 = 0; p2 < 4; p2++) {
            int o0 = og * 8 + p2 * 2;
            float s0 = 0.f, s1 = 0.f;
            #pragma unroll
            for (int k = 0; k < 16; k++) {
                s0 += xk[k] * W1[o0 * 16 + k];
                s1 += xk[k] * W1[o0 * 16 + 16 + k];
            }
            __half2 hh = __floats2half2_rn(s0 * dnl, s1 * dnl);
            uo[p2] = *(unsigned int*)&hh;
        }
        ((uint4*)hs1g)[((size_t)(g << 10) + ln) * 4 + og] = make_uint4(uo[0], uo[1], uo[2], uo[3]);
        *(uint2*)&hsLh[ln * 16 + ((( (2*og)     ^ s7own)) << 1)] = make_uint2(uo[0], uo[1]);
        *(uint2*)&hsLh[ln * 16 + ((( (2*og + 1) ^ s7own)) << 1)] = make_uint2(uo[2], uo[3]);
    }
    __syncthreads();   /* barrier drains vmem: hs1g stores issued before release */
    if (t == 0)
        __hip_atomic_fetch_add(arrive + g, 1, __ATOMIC_RELEASE, __HIP_MEMORY_SCOPE_AGENT);

    /* CSR build overlaps peers' staging */
    int dq = 0, r4 = 0;
    if (t < 256) { dq = hist[t]; r4 = (dq + 3) & ~3; }
    int lane = t & 63, wid = t >> 6;
    int xx = r4;
    #pragma unroll
    for (int off = 1; off < 64; off <<= 1) {
        int y = __shfl_up(xx, off, 64);
        if (lane >= off) xx += y;
    }
    if (t < 256 && lane == 63) wsum[wid] = xx;
    __syncthreads();
    if (t < 256) {
        int pre = 0;
        for (int w = 0; w < wid; w++) pre += wsum[w];
        lrow[t] = pre + xx - r4;
        lfill[t] = 0;
    }
    __syncthreads();
    for (int i = t; i < cnt; i += 1024) {
        unsigned int v = eb[i];
        int dl = (v >> 10) & 255;
        int pos = lrow[dl] + atomicAdd(&lfill[dl], 1);
        lcsr[pos] = (unsigned short)(v & 1023);
    }
    if (t < 256) {
        int st = lrow[t];
        for (int i = dq; i < r4; i++) lcsr[st + i] = 1024;
    }

    if (t == 0) {
        while (__hip_atomic_load(arrive + g, __ATOMIC_RELAXED, __HIP_MEMORY_SCOPE_AGENT) < 4) {}
        (void)__hip_atomic_load(arrive + g, __ATOMIC_ACQUIRE, __HIP_MEMORY_SCOPE_AGENT);
    }
    __syncthreads();

    /* pull the 3 peer quarters' staged rows into LDS */
    if (t < 768) {
        int r = (((part + 1) << 8) + t) & 1023;
        const uint4* s4 = (const uint4*)hs1g + ((size_t)(g << 10) + r) * 4;
        uint4 ua = s4[0], ub = s4[1], uc = s4[2], ud = s4[3];
        unsigned int u[16] = { ua.x, ua.y, ua.z, ua.w, ub.x, ub.y, ub.z, ub.w,
                               uc.x, uc.y, uc.z, uc.w, ud.x, ud.y, ud.z, ud.w };
        int s7 = r & 7;
        #pragma unroll
        for (int p = 0; p < 8; p++)
            *(uint2*)&hsLh[r * 16 + ((p ^ s7) << 1)] = make_uint2(u[2*p], u[2*p+1]);
    }
    __syncthreads();

    /* layer-1 gather (8 lanes/node) -> h1 transposed in LDS */
    int q = t & 7, grp = t >> 3;
    #pragma unroll
    for (int pass = 0; pass < 2; pass++) {
        int lq = pass * 128 + grp;
        int lnq = (part << 8) + lq;
        int d = hist[lq];
        float dn = disL[lq];
        int st = lrow[lq];
        float4 acc = ld4h(hsLh, lnq, q);
        const ushort4* c4 = (const ushort4*)(lcsr + st);
        int d4 = (d + 3) >> 2;
        for (int i = 0; i < d4; i++) {
            ushort4 ss = c4[i];
            float4 v0 = ld4h(hsLh, ss.x, q);
            float4 v1 = ld4h(hsLh, ss.y, q);
            float4 v2 = ld4h(hsLh, ss.z, q);
            float4 v3 = ld4h(hsLh, ss.w, q);
            acc.x += (v0.x + v1.x) + (v2.x + v3.x);
            acc.y += (v0.y + v1.y) + (v2.y + v3.y);
            acc.z += (v0.z + v1.z) + (v2.z + v3.z);
            acc.w += (v0.w + v1.w) + (v2.w + v3.w);
        }
        float4 bb = ((const float4*)b1)[q];
        h1T[(4*q+0)*257 + lq] = ftanh(dn * acc.x + bb.x);
        h1T[(4*q+1)*257 + lq] = ftanh(dn * acc.y + bb.y);
        h1T[(4*q+2)*257 + lq] = ftanh(dn * acc.z + bb.z);
        h1T[(4*q+3)*257 + lq] = ftanh(dn * acc.w + bb.w);
    }
    __syncthreads();

    /* stage hs2 = dis*(h1@W2^T) for own nodes */
    {
        float hk[32];
        #pragma unroll
        for (int k = 0; k < 32; k++) hk[k] = h1T[k*257 + nl];
        float dnl = disL[nl];
        unsigned int vo[4];
        #pragma unroll
        for (int p2 = 0; p2 < 4; p2++) {
            int o0 = og * 8 + p2 * 2;
            float s0 = 0.f, s1 = 0.f;
            #pragma unroll
            for (int k = 0; k < 32; k++) {
                s0 += hk[k] * W2L[o0*33 + k];
                s1 += hk[k] * W2L[(o0+1)*33 + k];
            }
            __half2 hh = __floats2half2_rn(s0 * dnl, s1 * dnl);
            vo[p2] = *(unsigned int*)&hh;
        }
        ((uint4*)hs2g)[((size_t)(g << 10) + ln) * 4 + og] = make_uint4(vo[0], vo[1], vo[2], vo[3]);
        *(uint2*)&hsLh[ln * 16 + ((( (2*og)     ^ s7own)) << 1)] = make_uint2(vo[0], vo[1]);
        *(uint2*)&hsLh[ln * 16 + ((( (2*og + 1) ^ s7own)) << 1)] = make_uint2(vo[2], vo[3]);
    }
    __syncthreads();
    if (t == 0) {
        __hip_atomic_fetch_add(arrive + 64 + g, 1, __ATOMIC_RELEASE, __HIP_MEMORY_SCOPE_AGENT);
        while (__hip_atomic_load(arrive + 64 + g, __ATOMIC_RELAXED, __HIP_MEMORY_SCOPE_AGENT) < 4) {}
        (void)__hip_atomic_load(arrive + 64 + g, __ATOMIC_ACQUIRE, __HIP_MEMORY_SCOPE_AGENT);
    }
    __syncthreads();

    if (t < 768) {
        int r = (((part + 1) << 8) + t) & 1023;
        const uint4* s4 = (const uint4*)hs2g + ((size_t)(g << 10) + r) * 4;
        uint4 ua = s4[0], ub = s4[1], uc = s4[2], ud = s4[3];
        unsigned int u[16] = { ua.x, ua.y, ua.z, ua.w, ub.x, ub.y, ub.z, ub.w,
                               uc.x, uc.y, uc.z, uc.w, ud.x, ud.y, ud.z, ud.w };
        int s7 = r & 7;
        #pragma unroll
        for (int p = 0; p < 8; p++)
            *(uint2*)&hsLh[r * 16 + ((p ^ s7) << 1)] = make_uint2(u[2*p], u[2*p+1]);
    }
    __syncthreads();

    /* layer-2 gather -> h2 into h1T */
    #pragma unroll
    for (int pass = 0; pass < 2; pass++) {
        int lq = pass * 128 + grp;
        int lnq = (part << 8) + lq;
        int d = hist[lq];
        float dn = disL[lq];
        int st = lrow[lq];
        float4 acc = ld4h(hsLh, lnq, q);
        const ushort4* c4 = (const ushort4*)(lcsr + st);
        int d4 = (d + 3) >> 2;
        for (int i = 0; i < d4; i++) {
            ushort4 ss = c4[i];
            float4 v0 = ld4h(hsLh, ss.x, q);
            float4 v1 = ld4h(hsLh, ss.y, q);
            float4 v2 = ld4h(hsLh, ss.z, q);
            float4 v3 = ld4h(hsLh, ss.w, q);
            acc.x += (v0.x + v1.x) + (v2.x + v3.x);
            acc.y += (v0.y + v1.y) + (v2.y + v3.y);
            acc.z += (v0.z + v1.z) + (v2.z + v3.z);
            acc.w += (v0.w + v1.w) + (v2.w + v3.w);
        }
        float4 bb = ((const float4*)b2)[q];
        h1T[(4*q+0)*257 + lq] = ftanh(dn * acc.x + bb.x);
        h1T[(4*q+1)*257 + lq] = ftanh(dn * acc.y + bb.y);
        h1T[(4*q+2)*257 + lq] = ftanh(dn * acc.z + bb.z);
        h1T[(4*q+3)*257 + lq] = ftanh(dn * acc.w + bb.w);
    }
    __syncthreads();

    /* h3 = tanh(h2 @ Wl^T + bl), pool own 256 nodes */
    int o = t & 31, seg = t >> 5;
    float wlr[32];
    #pragma unroll
    for (int k = 0; k < 32; k++) wlr[k] = Wl[o*32 + k];
    float blv = bl[o];
    float ps = 0.f;
    #pragma unroll
    for (int j = 0; j < 8; j++) {
        int nn = seg * 8 + j;
        float s = blv;
        #pragma unroll
        for (int k = 0; k < 32; k++) s += h1T[k*257 + nn] * wlr[k];
        ps += ftanh(s);
    }
    float* psum = (float*)hsLh;
    psum[t] = ps;
    __syncthreads();
    if (t < 32) {
        float tot = 0.f;
        for (int s2 = 0; s2 < 32; s2++) tot += psum[s2 * 32 + t];
        pooled4[(g * 4 + part) * 32 + t] = tot;
    }
}

/* whole MLP tail: 64 graphs x 32 lanes */
__global__ void k_final(const float* __restrict__ pooled4, const float* __restrict__ share,
                        const float* __restrict__ Wp,  const float* __restrict__ bp,
                        const float* __restrict__ Vw1, const float* __restrict__ Vb1,
                        const float* __restrict__ Vw2, const float* __restrict__ Vb2,
                        const float* __restrict__ Vw3, const float* __restrict__ Vb3,
                        const float* __restrict__ Cw1, const float* __restrict__ Cb1,
                        const float* __restrict__ Cw2, const float* __restrict__ Cb2,
                        float* __restrict__ out) {
    int id = blockIdx.x * 256 + threadIdx.x;  /* 0..2047 */
    int b = id >> 5;
    int j = id & 31;
    float p = pooled4[(b * 4 + 0) * 32 + j] + pooled4[(b * 4 + 1) * 32 + j]
            + pooled4[(b * 4 + 2) * 32 + j] + pooled4[(b * 4 + 3) * 32 + j];
    float h1v = bp[j];
    #pragma unroll
    for (int k = 0; k < 32; k++) h1v += Wp[j * 32 + k] * __shfl(p, k, 32);
    float s0 = share[b * 64 + j];
    float s1 = share[b * 64 + 32 + j];
    float t1 = Vb1[j];
    #pragma unroll
    for (int k = 0; k < 32; k++) {
        t1 += Vw1[j * 64 + k] * __shfl(s0, k, 32);
        t1 += Vw1[j * 64 + 32 + k] * __shfl(s1, k, 32);
    }
    t1 = tanhf(t1);
    float t2 = Vb2[j];
    #pragma unroll
    for (int k = 0; k < 32; k++) t2 += Vw2[j * 32 + k] * __shfl(t1, k, 32);
    t2 = tanhf(t2);
    float h2v = Vb3[j];
    #pragma unroll
    for (int k = 0; k < 32; k++) h2v += Vw3[j * 32 + k] * __shfl(t2, k, 32);
    float z = Cb1[j];
    #pragma unroll
    for (int k = 0; k < 32; k++) {
        z += Cw1[j * 64 + k] * __shfl(h1v, k, 32);
        z += Cw1[j * 64 + 32 + k] * __shfl(h2v, k, 32);
    }
    z = tanhf(z);
    float v = Cw2[j] * z;
    v += __shfl_down(v, 16, 32); v += __shfl_down(v, 8, 32);
    v += __shfl_down(v, 4, 32);  v += __shfl_down(v, 2, 32);
    v += __shfl_down(v, 1, 32);
    if (j == 0) out[b] = v + Cb2[0];
}

extern "C" void kernel_launch(void* const* d_in, const int* in_sizes, int n_in,
                              void* d_out, int out_size, void* d_ws, size_t ws_size,
                              hipStream_t stream) {
    const float* x     = (const float*)d_in[0];
    const int*   ei    = (const int*)d_in[1];
    const float* share = (const float*)d_in[3];
    const float* W1 = (const float*)d_in[4];  const float* b1 = (const float*)d_in[5];
    const float* W2 = (const float*)d_in[6];  const float* b2 = (const float*)d_in[7];
    const float* Wl = (const float*)d_in[8];  const float* bl = (const float*)d_in[9];
    const float* Wp = (const float*)d_in[10]; const float* bp = (const float*)d_in[11];
    const float* Vw1 = (const float*)d_in[12]; const float* Vb1 = (const float*)d_in[13];
    const float* Vw2 = (const float*)d_in[14]; const float* Vb2 = (const float*)d_in[15];
    const float* Vw3 = (const float*)d_in[16]; const float* Vb3 = (const float*)d_in[17];
    const float* Cw1 = (const float*)d_in[18]; const float* Cb1 = (const float*)d_in[19];
    const float* Cw2 = (const float*)d_in[20]; const float* Cb2 = (const float*)d_in[21];

    char* ws = (char*)d_ws;
    int*          gfill   = (int*)(ws + OFF_GFILL);
    int*          arrive  = (int*)(ws + OFF_ARR);
    float*        pooled4 = (float*)(ws + OFF_POOL4);
    unsigned int* ebuf    = (unsigned int*)(ws + OFF_EBUF);
    unsigned int* hs1g    = (unsigned int*)(ws + OFF_HS1);
    unsigned int* hs2g    = (unsigned int*)(ws + OFF_HS2);

    const int* srcp = ei;
    const int* dstp = ei + NEDGES;

    hipMemsetAsync(ws, 0, 1536, stream);  /* gfill[256] + arrive[128] */

    k_bucket<<<256, 256, 0, stream>>>(srcp, dstp, gfill, ebuf);
    k_gcn<<<256, 1024, 0, stream>>>(x, W1, b1, W2, b2, Wl, bl,
                                    ebuf, gfill, hs1g, hs2g, arrive, pooled4);
    k_final<<<8, 256, 0, stream>>>(pooled4, share, Wp, bp, Vw1, Vb1, Vw2, Vb2,
                                   Vw3, Vb3, Cw1, Cb1, Cw2, Cb2, (float*)d_out);
}